// Round 1
// baseline (1040.123 us; speedup 1.0000x reference)
//
#include <hip/hip_runtime.h>

#define N_NODES 100000
#define NUM_APS 1000
#define IN_F 32
#define HID 64

// ---------------- degree / norm ----------------
__global__ void deg_kernel(const int* __restrict__ col, const float* __restrict__ ew,
                           float* __restrict__ deg, int E) {
    int e = blockIdx.x * blockDim.x + threadIdx.x;
    if (e < E) atomicAdd(&deg[col[e]], ew[e]);
}

__global__ void dinv_kernel(const float* __restrict__ deg, float* __restrict__ dinv, int n) {
    int i = blockIdx.x * blockDim.x + threadIdx.x;
    if (i < n) {
        float d = deg[i];
        dinv[i] = d > 0.f ? 1.0f / sqrtf(d) : 0.f;
    }
}

__global__ void norm_kernel(const int* __restrict__ row, const int* __restrict__ col,
                            const float* __restrict__ ew, const float* __restrict__ dinv,
                            float* __restrict__ norm, int E) {
    int e = blockIdx.x * blockDim.x + threadIdx.x;
    if (e < E) norm[e] = dinv[row[e]] * ew[e] * dinv[col[e]];
}

// ---------------- propagation (scatter with atomics) ----------------
// 32 lanes per edge: lane f handles feature f. Coalesced gather + coalesced atomics.
__global__ void prop32(const int* __restrict__ row, const int* __restrict__ col,
                       const float* __restrict__ norm, const float* __restrict__ src,
                       float* __restrict__ dst, int E) {
    int t = blockIdx.x * blockDim.x + threadIdx.x;
    int e = t >> 5;
    if (e >= E) return;
    int f = t & 31;
    int c = col[e];
    float nm = norm[e];
    int r = row[e];
    atomicAdd(&dst[c * IN_F + f], src[r * IN_F + f] * nm);
}

// 64 lanes per edge; cmax filters destination rows (cmax=N_NODES -> full prop).
__global__ void prop64(const int* __restrict__ row, const int* __restrict__ col,
                       const float* __restrict__ norm, const float* __restrict__ src,
                       float* __restrict__ dst, int E, int cmax) {
    int t = blockIdx.x * blockDim.x + threadIdx.x;
    int e = t >> 6;
    if (e >= E) return;
    int c = col[e];
    if (c >= cmax) return;
    int f = t & 63;
    float nm = norm[e];
    int r = row[e];
    atomicAdd(&dst[c * HID + f], src[r * HID + f] * nm);
}

// ---------------- dense layers ----------------
// h1 = leaky_relu(x@w[0] + p1@w[1] + p2@w[2] + b), per-thread (node, out_feature)
__global__ __launch_bounds__(256) void dense1(const float* __restrict__ x,
                                              const float* __restrict__ p1,
                                              const float* __restrict__ p2,
                                              const float* __restrict__ w,
                                              const float* __restrict__ b,
                                              float* __restrict__ out) {
    __shared__ float sw[3 * IN_F * HID];  // 24 KB
    for (int i = threadIdx.x; i < 3 * IN_F * HID; i += 256) sw[i] = w[i];
    __syncthreads();
    int idx = blockIdx.x * 256 + threadIdx.x;
    int n = idx >> 6, f = idx & 63;
    if (n >= N_NODES) return;
    float acc = b[f];
    const float* xr = x + n * IN_F;
    const float* p1r = p1 + n * IN_F;
    const float* p2r = p2 + n * IN_F;
#pragma unroll
    for (int i = 0; i < IN_F; ++i) {
        acc += xr[i] * sw[i * HID + f];
        acc += p1r[i] * sw[IN_F * HID + i * HID + f];
        acc += p2r[i] * sw[2 * IN_F * HID + i * HID + f];
    }
    out[n * HID + f] = acc > 0.f ? acc : 0.01f * acc;
}

// ap = leaky_relu(h1@w[0] + q1@w[1] + q2@w[2] + b) for first NUM_APS nodes
__global__ __launch_bounds__(256) void dense2(const float* __restrict__ h1,
                                              const float* __restrict__ q1,
                                              const float* __restrict__ q2,
                                              const float* __restrict__ w,
                                              const float* __restrict__ b,
                                              float* __restrict__ ap) {
    __shared__ float sw[3 * HID * HID];  // 48 KB
    for (int i = threadIdx.x; i < 3 * HID * HID; i += 256) sw[i] = w[i];
    __syncthreads();
    int idx = blockIdx.x * 256 + threadIdx.x;
    int n = idx >> 6, f = idx & 63;
    if (n >= NUM_APS) return;
    float acc = b[f];
    const float* h = h1 + n * HID;
    const float* a = q1 + n * HID;
    const float* qq = q2 + n * HID;
#pragma unroll
    for (int i = 0; i < HID; ++i) {
        acc += h[i] * sw[i * HID + f];
        acc += a[i] * sw[HID * HID + i * HID + f];
        acc += qq[i] * sw[2 * HID * HID + i * HID + f];
    }
    acc = acc > 0.f ? acc : 0.01f * acc;
    ap[n * HID + f] = acc;
}

// two 64->3 heads; thread per (node, head_col)
__global__ void logits_kernel(const float* __restrict__ ap,
                              const float* __restrict__ wch, const float* __restrict__ bch,
                              const float* __restrict__ wpw, const float* __restrict__ bpw,
                              float* __restrict__ out) {
    int idx = blockIdx.x * blockDim.x + threadIdx.x;
    if (idx >= NUM_APS * 6) return;
    int n = idx / 6, j = idx % 6;
    const float* w;
    float bb;
    float* o;
    if (j < 3) {
        w = wch + j;
        bb = bch[j];
        o = out + n * 3 + j;
    } else {
        int jj = j - 3;
        w = wpw + jj;
        bb = bpw[jj];
        o = out + NUM_APS * 3 + n * 3 + jj;
    }
    float acc = bb;
    const float* a = ap + n * HID;
#pragma unroll
    for (int i = 0; i < HID; ++i) acc += a[i] * w[i * 3];
    *o = acc;
}

extern "C" void kernel_launch(void* const* d_in, const int* in_sizes, int n_in,
                              void* d_out, int out_size, void* d_ws, size_t ws_size,
                              hipStream_t stream) {
    const float* x   = (const float*)d_in[0];
    const int*   ei  = (const int*)d_in[1];
    const float* ea  = (const float*)d_in[2];
    const float* w1  = (const float*)d_in[3];
    const float* b1  = (const float*)d_in[4];
    const float* w2  = (const float*)d_in[5];
    const float* b2  = (const float*)d_in[6];
    const float* wch = (const float*)d_in[7];
    const float* bch = (const float*)d_in[8];
    const float* wpw = (const float*)d_in[9];
    const float* bpw = (const float*)d_in[10];

    const int E = in_sizes[2];           // 1,600,000
    const int* row = ei;                 // edge_index[0]
    const int* colv = ei + E;            // edge_index[1]

    // workspace layout (floats), with reuse:
    //   [0, 1.6M)          norm
    //   [1.6M, 1.7M)       deg            -> reused as q2 (64000)
    //   [1.7M, 1.8M)       dinv           -> reused as ap (64000)
    //   [1.8M, 5.0M)       p1 (100000x32) \__ reused as q1 (100000x64)
    //   [5.0M, 8.2M)       p2 (100000x32) /
    //   [8.2M, 14.6M)      h1 (100000x64)
    float* ws   = (float*)d_ws;
    float* norm = ws;
    float* deg  = ws + 1600000;
    float* dinv = ws + 1700000;
    float* p1   = ws + 1800000;
    float* p2   = ws + 5000000;
    float* h1   = ws + 8200000;
    float* q1   = p1;
    float* q2   = deg;
    float* ap   = dinv;

    // ---- gcn_norm ----
    hipMemsetAsync(deg, 0, N_NODES * sizeof(float), stream);
    deg_kernel<<<(E + 255) / 256, 256, 0, stream>>>(colv, ea, deg, E);
    dinv_kernel<<<(N_NODES + 255) / 256, 256, 0, stream>>>(deg, dinv, N_NODES);
    norm_kernel<<<(E + 255) / 256, 256, 0, stream>>>(row, colv, ea, dinv, norm, E);

    // ---- layer 1 propagations (width 32) ----
    hipMemsetAsync(p1, 0, (size_t)2 * N_NODES * IN_F * sizeof(float), stream);  // p1+p2
    {
        long long t = (long long)E * IN_F;
        prop32<<<(int)((t + 255) / 256), 256, 0, stream>>>(row, colv, norm, x, p1, E);
        prop32<<<(int)((t + 255) / 256), 256, 0, stream>>>(row, colv, norm, p1, p2, E);
    }
    dense1<<<(N_NODES * HID + 255) / 256, 256, 0, stream>>>(x, p1, p2, w1, b1, h1);

    // ---- layer 2 propagations (width 64); q1 reuses p1/p2 region ----
    hipMemsetAsync(q1, 0, (size_t)N_NODES * HID * sizeof(float), stream);
    hipMemsetAsync(q2, 0, (size_t)NUM_APS * HID * sizeof(float), stream);
    {
        long long t = (long long)E * HID;
        prop64<<<(int)((t + 255) / 256), 256, 0, stream>>>(row, colv, norm, h1, q1, E, N_NODES);
        prop64<<<(int)((t + 255) / 256), 256, 0, stream>>>(row, colv, norm, q1, q2, E, NUM_APS);
    }
    dense2<<<(NUM_APS * HID + 255) / 256, 256, 0, stream>>>(h1, q1, q2, w2, b2, ap);

    // ---- heads ----
    logits_kernel<<<(NUM_APS * 6 + 255) / 256, 256, 0, stream>>>(ap, wch, bch, wpw, bpw,
                                                                 (float*)d_out);
}

// Round 3
// 636.887 us; speedup vs baseline: 1.6331x; 1.6331x over previous
//
#include <hip/hip_runtime.h>
#include <hip/hip_bf16.h>

#define N_NODES 100000
#define NUM_APS 1000
#define IN_F 32
#define HID 64
#define SCAN_BLKS ((N_NODES + 255) / 256)  // 391

typedef __hip_bfloat16 bf16;

__device__ __forceinline__ float b2f(bf16 v) { return __bfloat162float(v); }

// ---------- CSR build ----------
__global__ void cnt_deg_k(const int* __restrict__ col, const float* __restrict__ ew,
                          int* __restrict__ cnt, float* __restrict__ deg, int E) {
    int e = blockIdx.x * blockDim.x + threadIdx.x;
    if (e < E) {
        int c = col[e];
        atomicAdd(&cnt[c], 1);
        atomicAdd(&deg[c], ew[e]);
    }
}

__global__ void dinv_k(const float* __restrict__ deg, float* __restrict__ dinv, int n) {
    int i = blockIdx.x * blockDim.x + threadIdx.x;
    if (i < n) {
        float d = deg[i];
        dinv[i] = d > 0.f ? 1.0f / sqrtf(d) : 0.f;
    }
}

// inclusive scan within 256-blocks; block totals to bsum
__global__ __launch_bounds__(256) void scan1_k(const int* __restrict__ cnt,
                                               int* __restrict__ off, int* __restrict__ bsum) {
    __shared__ int s[256];
    int i = blockIdx.x * 256 + threadIdx.x;
    int v = (i < N_NODES) ? cnt[i] : 0;
    s[threadIdx.x] = v;
    __syncthreads();
    for (int d = 1; d < 256; d <<= 1) {
        int t = (threadIdx.x >= d) ? s[threadIdx.x - d] : 0;
        __syncthreads();
        s[threadIdx.x] += t;
        __syncthreads();
    }
    if (i < N_NODES) off[i] = s[threadIdx.x];
    if (threadIdx.x == 255) bsum[blockIdx.x] = s[255];
}

// exclusive scan of the 391 block sums (single block)
__global__ __launch_bounds__(512) void scan2_k(int* __restrict__ bsum) {
    __shared__ int s[512];
    int v = (threadIdx.x < SCAN_BLKS) ? bsum[threadIdx.x] : 0;
    s[threadIdx.x] = v;
    __syncthreads();
    for (int d = 1; d < 512; d <<= 1) {
        int t = (threadIdx.x >= d) ? s[threadIdx.x - d] : 0;
        __syncthreads();
        s[threadIdx.x] += t;
        __syncthreads();
    }
    if (threadIdx.x < SCAN_BLKS) bsum[threadIdx.x] = s[threadIdx.x] - v;
}

// convert to global exclusive offsets
__global__ void scan3_k(const int* __restrict__ cnt, int* __restrict__ off,
                        const int* __restrict__ bsum) {
    int i = blockIdx.x * 256 + threadIdx.x;
    if (i < N_NODES) off[i] = off[i] - cnt[i] + bsum[blockIdx.x];
}

// scatter edges into CSR order; post-increment turns off[] into segment ENDS:
// after this kernel, segment(n) = [ n ? off[n-1] : 0,  off[n] )
__global__ void scatter_k(const int* __restrict__ row, const int* __restrict__ col,
                          const float* __restrict__ ew, const float* __restrict__ dinv,
                          int* __restrict__ off, int2* __restrict__ edat, int E) {
    int e = blockIdx.x * blockDim.x + threadIdx.x;
    if (e >= E) return;
    int c = col[e], r = row[e];
    int pos = atomicAdd(&off[c], 1);
    float nm = dinv[r] * ew[e] * dinv[c];
    edat[pos] = make_int2(r, __float_as_int(nm));
}

__global__ void f2b_k(const float* __restrict__ in, bf16* __restrict__ out, int n) {
    int i = blockIdx.x * blockDim.x + threadIdx.x;
    if (i < n) out[i] = __float2bfloat16(in[i]);
}

// ---------- gather propagation ----------
// half-wave (32 lanes) per node, feature = lane
__global__ __launch_bounds__(256) void gath32_k(const int2* __restrict__ edat,
                                                const int* __restrict__ off,
                                                const bf16* __restrict__ src,
                                                bf16* __restrict__ dst, int nn) {
    int t = blockIdx.x * 256 + threadIdx.x;
    int n = t >> 5;
    if (n >= nn) return;
    int f = t & 31;
    int s = (n == 0) ? 0 : off[n - 1];
    int e = off[n];
    float acc = 0.f;
    for (int i = s; i < e; ++i) {
        int2 v = edat[i];
        acc += __int_as_float(v.y) * b2f(src[v.x * IN_F + f]);
    }
    dst[n * IN_F + f] = __float2bfloat16(acc);
}

// full wave (64 lanes) per node
__global__ __launch_bounds__(256) void gath64_k(const int2* __restrict__ edat,
                                                const int* __restrict__ off,
                                                const bf16* __restrict__ src,
                                                bf16* __restrict__ dst, int nn) {
    int t = blockIdx.x * 256 + threadIdx.x;
    int n = t >> 6;
    if (n >= nn) return;
    int f = t & 63;
    int s = (n == 0) ? 0 : off[n - 1];
    int e = off[n];
    float acc = 0.f;
    for (int i = s; i < e; ++i) {
        int2 v = edat[i];
        acc += __int_as_float(v.y) * b2f(src[v.x * HID + f]);
    }
    dst[n * HID + f] = __float2bfloat16(acc);
}

// ---------- dense layers ----------
// h1 = lrelu(x@w0 + p1@w1 + p2@w2 + b); 4 nodes per 256-block
__global__ __launch_bounds__(256) void dense1_k(const bf16* __restrict__ xb,
                                                const bf16* __restrict__ p1,
                                                const bf16* __restrict__ p2,
                                                const float* __restrict__ w,
                                                const float* __restrict__ b,
                                                bf16* __restrict__ h1) {
    __shared__ float sw[3 * IN_F * HID];  // 24 KB
    __shared__ float sx[4][3 * IN_F];
    for (int i = threadIdx.x; i < 3 * IN_F * HID; i += 256) sw[i] = w[i];
    int nb = blockIdx.x * 4;
    for (int k = threadIdx.x; k < 4 * 96; k += 256) {
        int ln = k / 96, j = k % 96;
        int n = nb + ln;
        float v = 0.f;
        if (n < N_NODES) {
            int hop = j >> 5, ii = j & 31;
            const bf16* sp = (hop == 0) ? xb : (hop == 1 ? p1 : p2);
            v = b2f(sp[n * IN_F + ii]);
        }
        sx[ln][j] = v;
    }
    __syncthreads();
    int ln = threadIdx.x >> 6;
    int n = nb + ln;
    if (n >= N_NODES) return;
    int f = threadIdx.x & 63;
    float acc = b[f];
#pragma unroll 8
    for (int j = 0; j < 96; ++j) acc += sx[ln][j] * sw[j * HID + f];
    acc = acc > 0.f ? acc : 0.01f * acc;
    h1[n * HID + f] = __float2bfloat16(acc);
}

// ap = lrelu(h1@w0 + q1@w1 + q2@w2 + b) for first NUM_APS nodes; fp32 out
__global__ __launch_bounds__(256) void dense2_k(const bf16* __restrict__ h1,
                                                const bf16* __restrict__ q1,
                                                const bf16* __restrict__ q2,
                                                const float* __restrict__ w,
                                                const float* __restrict__ b,
                                                float* __restrict__ ap) {
    __shared__ float sw[3 * HID * HID];  // 48 KB
    __shared__ float sx[4][3 * HID];
    for (int i = threadIdx.x; i < 3 * HID * HID; i += 256) sw[i] = w[i];
    int nb = blockIdx.x * 4;
    for (int k = threadIdx.x; k < 4 * 192; k += 256) {
        int ln = k / 192, j = k % 192;
        int n = nb + ln;
        float v = 0.f;
        if (n < NUM_APS) {
            int hop = j >> 6, ii = j & 63;
            const bf16* sp = (hop == 0) ? h1 : (hop == 1 ? q1 : q2);
            v = b2f(sp[n * HID + ii]);
        }
        sx[ln][j] = v;
    }
    __syncthreads();
    int ln = threadIdx.x >> 6;
    int n = nb + ln;
    if (n >= NUM_APS) return;
    int f = threadIdx.x & 63;
    float acc = b[f];
#pragma unroll 8
    for (int j = 0; j < 192; ++j) acc += sx[ln][j] * sw[j * HID + f];
    acc = acc > 0.f ? acc : 0.01f * acc;
    ap[n * HID + f] = acc;
}

// two 64->3 heads
__global__ void logits_k(const float* __restrict__ ap,
                         const float* __restrict__ wch, const float* __restrict__ bch,
                         const float* __restrict__ wpw, const float* __restrict__ bpw,
                         float* __restrict__ out) {
    int idx = blockIdx.x * blockDim.x + threadIdx.x;
    if (idx >= NUM_APS * 6) return;
    int n = idx / 6, j = idx % 6;
    const float* w;
    float bb;
    float* o;
    if (j < 3) {
        w = wch + j;
        bb = bch[j];
        o = out + n * 3 + j;
    } else {
        int jj = j - 3;
        w = wpw + jj;
        bb = bpw[jj];
        o = out + NUM_APS * 3 + n * 3 + jj;
    }
    float acc = bb;
    const float* a = ap + n * HID;
#pragma unroll
    for (int i = 0; i < HID; ++i) acc += a[i] * w[i * 3];
    *o = acc;
}

extern "C" void kernel_launch(void* const* d_in, const int* in_sizes, int n_in,
                              void* d_out, int out_size, void* d_ws, size_t ws_size,
                              hipStream_t stream) {
    const float* x   = (const float*)d_in[0];
    const int*   ei  = (const int*)d_in[1];
    const float* ea  = (const float*)d_in[2];
    const float* w1  = (const float*)d_in[3];
    const float* b1  = (const float*)d_in[4];
    const float* w2  = (const float*)d_in[5];
    const float* b2  = (const float*)d_in[6];
    const float* wch = (const float*)d_in[7];
    const float* bch = (const float*)d_in[8];
    const float* wpw = (const float*)d_in[9];
    const float* bpw = (const float*)d_in[10];

    const int E = in_sizes[2];  // 1,600,000
    const int* row  = ei;
    const int* colv = ei + E;

    // ---- workspace layout (float units) ----
    // edat: 2E | off: N | cnt: N (→q2 bf16) | deg: N (→ap f32) | dinv: N | bsum: 512 |
    // xb: N*16 | p1b: N*16 \__ q1b (N*32) spans p1b..p2b
    //          | p2b: N*16 /
    // h1b: N*32            total ≈ 11.6M floats ≈ 46.5 MB
    float* ws = (float*)d_ws;
    int2*  edat = (int2*)ws;                       // 2E floats
    int*   off  = (int*)(ws + 2 * (size_t)E);      // N
    int*   cnt  = off + N_NODES;                   // N
    float* deg  = (float*)(cnt + N_NODES);         // N
    float* dinv = deg + N_NODES;                   // N
    int*   bsum = (int*)(dinv + N_NODES);          // 512
    bf16*  xb   = (bf16*)(bsum + 512);             // N*32 bf16 = N*16 floats
    bf16*  p1b  = xb + (size_t)N_NODES * IN_F;
    bf16*  p2b  = p1b + (size_t)N_NODES * IN_F;
    bf16*  h1b  = p2b + (size_t)N_NODES * IN_F;    // N*64 bf16
    bf16*  q1b  = p1b;                             // reuse p1b∪p2b (N*64 bf16)
    bf16*  q2b  = (bf16*)cnt;                      // 64000 bf16, reuse cnt
    float* ap   = deg;                             // 64000 f32, reuse deg

    // ---- CSR build + gcn_norm ----
    hipMemsetAsync(cnt, 0, 2 * (size_t)N_NODES * sizeof(int), stream);  // cnt + deg
    cnt_deg_k<<<(E + 255) / 256, 256, 0, stream>>>(colv, ea, cnt, deg, E);
    dinv_k<<<SCAN_BLKS, 256, 0, stream>>>(deg, dinv, N_NODES);
    scan1_k<<<SCAN_BLKS, 256, 0, stream>>>(cnt, off, bsum);
    scan2_k<<<1, 512, 0, stream>>>(bsum);
    scan3_k<<<SCAN_BLKS, 256, 0, stream>>>(cnt, off, bsum);
    scatter_k<<<(E + 255) / 256, 256, 0, stream>>>(row, colv, ea, dinv, off, edat, E);

    // ---- layer 1 ----
    f2b_k<<<(N_NODES * IN_F + 255) / 256, 256, 0, stream>>>(x, xb, N_NODES * IN_F);
    gath32_k<<<(N_NODES * 32 + 255) / 256, 256, 0, stream>>>(edat, off, xb, p1b, N_NODES);
    gath32_k<<<(N_NODES * 32 + 255) / 256, 256, 0, stream>>>(edat, off, p1b, p2b, N_NODES);
    dense1_k<<<(N_NODES + 3) / 4, 256, 0, stream>>>(xb, p1b, p2b, w1, b1, h1b);

    // ---- layer 2 ----
    gath64_k<<<(N_NODES * 64 + 255) / 256, 256, 0, stream>>>(edat, off, h1b, q1b, N_NODES);
    gath64_k<<<(NUM_APS * 64 + 255) / 256, 256, 0, stream>>>(edat, off, q1b, q2b, NUM_APS);
    dense2_k<<<(NUM_APS + 3) / 4, 256, 0, stream>>>(h1b, q1b, q2b, w2, b2, ap);

    // ---- heads ----
    logits_k<<<(NUM_APS * 6 + 255) / 256, 256, 0, stream>>>(ap, wch, bch, wpw, bpw,
                                                            (float*)d_out);
}

// Round 4
// 423.949 us; speedup vs baseline: 2.4534x; 1.5023x over previous
//
#include <hip/hip_runtime.h>
#include <hip/hip_bf16.h>

#define N_NODES 100000
#define NUM_APS 1000
#define IN_F 32
#define HID 64
#define SCAN_BLKS ((N_NODES + 255) / 256)  // 391

typedef __hip_bfloat16 bf16;

__device__ __forceinline__ float b2f(bf16 v) { return __bfloat162float(v); }
// bf16 pair decode: low/high halves of a uint
__device__ __forceinline__ float blo(unsigned u) { return __uint_as_float(u << 16); }
__device__ __forceinline__ float bhi(unsigned u) { return __uint_as_float(u & 0xffff0000u); }
__device__ __forceinline__ unsigned packbf(float x, float y) {
    bf16 a = __float2bfloat16(x), b = __float2bfloat16(y);
    unsigned short ua = *reinterpret_cast<unsigned short*>(&a);
    unsigned short ub = *reinterpret_cast<unsigned short*>(&b);
    return (unsigned)ua | ((unsigned)ub << 16);
}

// ---------- CSR build ----------
__global__ void cnt_deg_k(const int* __restrict__ col, const float* __restrict__ ew,
                          int* __restrict__ cnt, float* __restrict__ deg, int E) {
    int e = blockIdx.x * blockDim.x + threadIdx.x;
    if (e < E) {
        int c = col[e];
        atomicAdd(&cnt[c], 1);
        atomicAdd(&deg[c], ew[e]);
    }
}

__global__ void dinv_k(const float* __restrict__ deg, float* __restrict__ dinv, int n) {
    int i = blockIdx.x * blockDim.x + threadIdx.x;
    if (i < n) {
        float d = deg[i];
        dinv[i] = d > 0.f ? 1.0f / sqrtf(d) : 0.f;
    }
}

// inclusive scan within 256-blocks; block totals to bsum
__global__ __launch_bounds__(256) void scan1_k(const int* __restrict__ cnt,
                                               int* __restrict__ off, int* __restrict__ bsum) {
    __shared__ int s[256];
    int i = blockIdx.x * 256 + threadIdx.x;
    int v = (i < N_NODES) ? cnt[i] : 0;
    s[threadIdx.x] = v;
    __syncthreads();
    for (int d = 1; d < 256; d <<= 1) {
        int t = (threadIdx.x >= d) ? s[threadIdx.x - d] : 0;
        __syncthreads();
        s[threadIdx.x] += t;
        __syncthreads();
    }
    if (i < N_NODES) off[i] = s[threadIdx.x];
    if (threadIdx.x == 255) bsum[blockIdx.x] = s[255];
}

// exclusive scan of the 391 block sums (single block)
__global__ __launch_bounds__(512) void scan2_k(int* __restrict__ bsum) {
    __shared__ int s[512];
    int v = (threadIdx.x < SCAN_BLKS) ? bsum[threadIdx.x] : 0;
    s[threadIdx.x] = v;
    __syncthreads();
    for (int d = 1; d < 512; d <<= 1) {
        int t = (threadIdx.x >= d) ? s[threadIdx.x - d] : 0;
        __syncthreads();
        s[threadIdx.x] += t;
        __syncthreads();
    }
    if (threadIdx.x < SCAN_BLKS) bsum[threadIdx.x] = s[threadIdx.x] - v;
}

// convert to global exclusive offsets
__global__ void scan3_k(const int* __restrict__ cnt, int* __restrict__ off,
                        const int* __restrict__ bsum) {
    int i = blockIdx.x * 256 + threadIdx.x;
    if (i < N_NODES) off[i] = off[i] - cnt[i] + bsum[blockIdx.x];
}

// scatter edges into CSR order; post-increment turns off[] into segment ENDS:
// after this kernel, segment(n) = [ n ? off[n-1] : 0,  off[n] )
__global__ void scatter_k(const int* __restrict__ row, const int* __restrict__ col,
                          const float* __restrict__ ew, const float* __restrict__ dinv,
                          int* __restrict__ off, int2* __restrict__ edat, int E) {
    int e = blockIdx.x * blockDim.x + threadIdx.x;
    if (e >= E) return;
    int c = col[e], r = row[e];
    int pos = atomicAdd(&off[c], 1);
    float nm = dinv[r] * ew[e] * dinv[c];
    edat[pos] = make_int2(r, __float_as_int(nm));
}

__global__ void f2b_k(const float* __restrict__ in, bf16* __restrict__ out, int n) {
    int i = blockIdx.x * blockDim.x + threadIdx.x;
    if (i < n) out[i] = __float2bfloat16(in[i]);
}

// ---------- gather propagation (latency-optimized) ----------
// src/dst viewed as uint rows of bf16 PAIRS. gath32: 16 pair-lanes per node
// (4 nodes/wave); gath64: 32 pair-lanes per node (2 nodes/wave).
// Unroll-4: 4 independent edat loads -> 4 independent gathers -> FMAs.
__global__ __launch_bounds__(256) void gath32_k(const int2* __restrict__ edat,
                                                const int* __restrict__ off,
                                                const unsigned* __restrict__ src,
                                                unsigned* __restrict__ dst, int nn) {
    int t = blockIdx.x * 256 + threadIdx.x;
    int n = t >> 4;
    if (n >= nn) return;
    int fp = t & 15;  // pair index within row of 16 uints
    int s = (n == 0) ? 0 : off[n - 1];
    int e = off[n];
    float a0 = 0.f, a1 = 0.f, b0 = 0.f, b1 = 0.f;
    int i = s;
    for (; i + 4 <= e; i += 4) {
        int2 v0 = edat[i], v1 = edat[i + 1], v2 = edat[i + 2], v3 = edat[i + 3];
        unsigned s0 = src[v0.x * 16 + fp];
        unsigned s1 = src[v1.x * 16 + fp];
        unsigned s2 = src[v2.x * 16 + fp];
        unsigned s3 = src[v3.x * 16 + fp];
        float n0 = __int_as_float(v0.y), n1 = __int_as_float(v1.y);
        float n2 = __int_as_float(v2.y), n3 = __int_as_float(v3.y);
        a0 += n0 * blo(s0); a1 += n0 * bhi(s0);
        b0 += n1 * blo(s1); b1 += n1 * bhi(s1);
        a0 += n2 * blo(s2); a1 += n2 * bhi(s2);
        b0 += n3 * blo(s3); b1 += n3 * bhi(s3);
    }
    for (; i < e; ++i) {
        int2 v = edat[i];
        unsigned sv = src[v.x * 16 + fp];
        float nm = __int_as_float(v.y);
        a0 += nm * blo(sv); a1 += nm * bhi(sv);
    }
    a0 += b0; a1 += b1;
    dst[n * 16 + fp] = packbf(a0, a1);
}

__global__ __launch_bounds__(256) void gath64_k(const int2* __restrict__ edat,
                                                const int* __restrict__ off,
                                                const unsigned* __restrict__ src,
                                                unsigned* __restrict__ dst, int nn) {
    int t = blockIdx.x * 256 + threadIdx.x;
    int n = t >> 5;
    if (n >= nn) return;
    int fp = t & 31;  // pair index within row of 32 uints
    int s = (n == 0) ? 0 : off[n - 1];
    int e = off[n];
    float a0 = 0.f, a1 = 0.f, b0 = 0.f, b1 = 0.f;
    int i = s;
    for (; i + 4 <= e; i += 4) {
        int2 v0 = edat[i], v1 = edat[i + 1], v2 = edat[i + 2], v3 = edat[i + 3];
        unsigned s0 = src[v0.x * 32 + fp];
        unsigned s1 = src[v1.x * 32 + fp];
        unsigned s2 = src[v2.x * 32 + fp];
        unsigned s3 = src[v3.x * 32 + fp];
        float n0 = __int_as_float(v0.y), n1 = __int_as_float(v1.y);
        float n2 = __int_as_float(v2.y), n3 = __int_as_float(v3.y);
        a0 += n0 * blo(s0); a1 += n0 * bhi(s0);
        b0 += n1 * blo(s1); b1 += n1 * bhi(s1);
        a0 += n2 * blo(s2); a1 += n2 * bhi(s2);
        b0 += n3 * blo(s3); b1 += n3 * bhi(s3);
    }
    for (; i < e; ++i) {
        int2 v = edat[i];
        unsigned sv = src[v.x * 32 + fp];
        float nm = __int_as_float(v.y);
        a0 += nm * blo(sv); a1 += nm * bhi(sv);
    }
    a0 += b0; a1 += b1;
    dst[n * 32 + fp] = packbf(a0, a1);
}

// ---------- dense layers ----------
// h1 = lrelu(x@w0 + p1@w1 + p2@w2 + b); 4 nodes per 256-block
__global__ __launch_bounds__(256) void dense1_k(const bf16* __restrict__ xb,
                                                const bf16* __restrict__ p1,
                                                const bf16* __restrict__ p2,
                                                const float* __restrict__ w,
                                                const float* __restrict__ b,
                                                bf16* __restrict__ h1) {
    __shared__ float sw[3 * IN_F * HID];  // 24 KB
    __shared__ float sx[4][3 * IN_F];
    for (int i = threadIdx.x; i < 3 * IN_F * HID; i += 256) sw[i] = w[i];
    int nb = blockIdx.x * 4;
    for (int k = threadIdx.x; k < 4 * 96; k += 256) {
        int ln = k / 96, j = k % 96;
        int n = nb + ln;
        float v = 0.f;
        if (n < N_NODES) {
            int hop = j >> 5, ii = j & 31;
            const bf16* sp = (hop == 0) ? xb : (hop == 1 ? p1 : p2);
            v = b2f(sp[n * IN_F + ii]);
        }
        sx[ln][j] = v;
    }
    __syncthreads();
    int ln = threadIdx.x >> 6;
    int n = nb + ln;
    if (n >= N_NODES) return;
    int f = threadIdx.x & 63;
    float acc = b[f];
#pragma unroll 8
    for (int j = 0; j < 96; ++j) acc += sx[ln][j] * sw[j * HID + f];
    acc = acc > 0.f ? acc : 0.01f * acc;
    h1[n * HID + f] = __float2bfloat16(acc);
}

// ap = lrelu(h1@w0 + q1@w1 + q2@w2 + b) for first NUM_APS nodes; fp32 out
__global__ __launch_bounds__(256) void dense2_k(const bf16* __restrict__ h1,
                                                const bf16* __restrict__ q1,
                                                const bf16* __restrict__ q2,
                                                const float* __restrict__ w,
                                                const float* __restrict__ b,
                                                float* __restrict__ ap) {
    __shared__ float sw[3 * HID * HID];  // 48 KB
    __shared__ float sx[4][3 * HID];
    for (int i = threadIdx.x; i < 3 * HID * HID; i += 256) sw[i] = w[i];
    int nb = blockIdx.x * 4;
    for (int k = threadIdx.x; k < 4 * 192; k += 256) {
        int ln = k / 192, j = k % 192;
        int n = nb + ln;
        float v = 0.f;
        if (n < NUM_APS) {
            int hop = j >> 6, ii = j & 63;
            const bf16* sp = (hop == 0) ? h1 : (hop == 1 ? q1 : q2);
            v = b2f(sp[n * HID + ii]);
        }
        sx[ln][j] = v;
    }
    __syncthreads();
    int ln = threadIdx.x >> 6;
    int n = nb + ln;
    if (n >= NUM_APS) return;
    int f = threadIdx.x & 63;
    float acc = b[f];
#pragma unroll 8
    for (int j = 0; j < 192; ++j) acc += sx[ln][j] * sw[j * HID + f];
    acc = acc > 0.f ? acc : 0.01f * acc;
    ap[n * HID + f] = acc;
}

// two 64->3 heads
__global__ void logits_k(const float* __restrict__ ap,
                         const float* __restrict__ wch, const float* __restrict__ bch,
                         const float* __restrict__ wpw, const float* __restrict__ bpw,
                         float* __restrict__ out) {
    int idx = blockIdx.x * blockDim.x + threadIdx.x;
    if (idx >= NUM_APS * 6) return;
    int n = idx / 6, j = idx % 6;
    const float* w;
    float bb;
    float* o;
    if (j < 3) {
        w = wch + j;
        bb = bch[j];
        o = out + n * 3 + j;
    } else {
        int jj = j - 3;
        w = wpw + jj;
        bb = bpw[jj];
        o = out + NUM_APS * 3 + n * 3 + jj;
    }
    float acc = bb;
    const float* a = ap + n * HID;
#pragma unroll
    for (int i = 0; i < HID; ++i) acc += a[i] * w[i * 3];
    *o = acc;
}

extern "C" void kernel_launch(void* const* d_in, const int* in_sizes, int n_in,
                              void* d_out, int out_size, void* d_ws, size_t ws_size,
                              hipStream_t stream) {
    const float* x   = (const float*)d_in[0];
    const int*   ei  = (const int*)d_in[1];
    const float* ea  = (const float*)d_in[2];
    const float* w1  = (const float*)d_in[3];
    const float* b1  = (const float*)d_in[4];
    const float* w2  = (const float*)d_in[5];
    const float* b2  = (const float*)d_in[6];
    const float* wch = (const float*)d_in[7];
    const float* bch = (const float*)d_in[8];
    const float* wpw = (const float*)d_in[9];
    const float* bpw = (const float*)d_in[10];

    const int E = in_sizes[2];  // 1,600,000
    const int* row  = ei;
    const int* colv = ei + E;

    // ---- workspace layout (float units) ----
    float* ws = (float*)d_ws;
    int2*  edat = (int2*)ws;                       // 2E floats
    int*   off  = (int*)(ws + 2 * (size_t)E);      // N
    int*   cnt  = off + N_NODES;                   // N
    float* deg  = (float*)(cnt + N_NODES);         // N
    float* dinv = deg + N_NODES;                   // N
    int*   bsum = (int*)(dinv + N_NODES);          // 512
    bf16*  xb   = (bf16*)(bsum + 512);             // N*32 bf16
    bf16*  p1b  = xb + (size_t)N_NODES * IN_F;
    bf16*  p2b  = p1b + (size_t)N_NODES * IN_F;
    bf16*  h1b  = p2b + (size_t)N_NODES * IN_F;    // N*64 bf16
    bf16*  q1b  = p1b;                             // reuse p1b∪p2b (N*64 bf16)
    bf16*  q2b  = (bf16*)cnt;                      // 64000 bf16, reuse cnt
    float* ap   = deg;                             // 64000 f32, reuse deg

    // ---- CSR build + gcn_norm ----
    hipMemsetAsync(cnt, 0, 2 * (size_t)N_NODES * sizeof(int), stream);  // cnt + deg
    cnt_deg_k<<<(E + 255) / 256, 256, 0, stream>>>(colv, ea, cnt, deg, E);
    dinv_k<<<SCAN_BLKS, 256, 0, stream>>>(deg, dinv, N_NODES);
    scan1_k<<<SCAN_BLKS, 256, 0, stream>>>(cnt, off, bsum);
    scan2_k<<<1, 512, 0, stream>>>(bsum);
    scan3_k<<<SCAN_BLKS, 256, 0, stream>>>(cnt, off, bsum);
    scatter_k<<<(E + 255) / 256, 256, 0, stream>>>(row, colv, ea, dinv, off, edat, E);

    // ---- layer 1 (16 pair-lanes per node) ----
    f2b_k<<<(N_NODES * IN_F + 255) / 256, 256, 0, stream>>>(x, xb, N_NODES * IN_F);
    gath32_k<<<(N_NODES * 16 + 255) / 256, 256, 0, stream>>>(edat, off, (unsigned*)xb,
                                                             (unsigned*)p1b, N_NODES);
    gath32_k<<<(N_NODES * 16 + 255) / 256, 256, 0, stream>>>(edat, off, (unsigned*)p1b,
                                                             (unsigned*)p2b, N_NODES);
    dense1_k<<<(N_NODES + 3) / 4, 256, 0, stream>>>(xb, p1b, p2b, w1, b1, h1b);

    // ---- layer 2 (32 pair-lanes per node) ----
    gath64_k<<<(N_NODES * 32 + 255) / 256, 256, 0, stream>>>(edat, off, (unsigned*)h1b,
                                                             (unsigned*)q1b, N_NODES);
    gath64_k<<<(NUM_APS * 32 + 255) / 256, 256, 0, stream>>>(edat, off, (unsigned*)q1b,
                                                             (unsigned*)q2b, NUM_APS);
    dense2_k<<<(NUM_APS + 3) / 4, 256, 0, stream>>>(h1b, q1b, q2b, w2, b2, ap);

    // ---- heads ----
    logits_k<<<(NUM_APS * 6 + 255) / 256, 256, 0, stream>>>(ap, wch, bch, wpw, bpw,
                                                            (float*)d_out);
}

// Round 7
// 366.078 us; speedup vs baseline: 2.8413x; 1.1581x over previous
//
#include <hip/hip_runtime.h>
#include <hip/hip_bf16.h>

#define N_NODES 100000
#define NUM_APS 1000
#define IN_F 32
#define HID 64
#define SCAN_BLKS ((N_NODES + 255) / 256)  // 391
#define MASK40 ((1ull << 40) - 1)

typedef __hip_bfloat16 bf16;
typedef unsigned long long ull;

__device__ __forceinline__ float b2f(bf16 v) { return __bfloat162float(v); }
// bf16 pair decode: low/high halves of a uint
__device__ __forceinline__ float blo(unsigned u) { return __uint_as_float(u << 16); }
__device__ __forceinline__ float bhi(unsigned u) { return __uint_as_float(u & 0xffff0000u); }
__device__ __forceinline__ unsigned packbf(float x, float y) {
    bf16 a = __float2bfloat16(x), b = __float2bfloat16(y);
    unsigned short ua = *reinterpret_cast<unsigned short*>(&a);
    unsigned short ub = *reinterpret_cast<unsigned short*>(&b);
    return (unsigned)ua | ((unsigned)ub << 16);
}

// ---------- CSR build ----------
// NEW vs round-3: count+deg merged into ONE 64-bit atomic per edge.
// high 24 bits: edge count; low 40 bits: sum of ew in 2^-24 fixed point
// (per-node deg < 64 weights < 2^6 * 2^24 = 2^30 << 2^40, no carry into count).
__global__ void cntdeg_pack_k(const int* __restrict__ col, const float* __restrict__ ew,
                              ull* __restrict__ packed, int E) {
    int e = blockIdx.x * blockDim.x + threadIdx.x;
    if (e < E) {
        ull add = (1ull << 40) | (ull)(ew[e] * 16777216.0f);
        atomicAdd(&packed[col[e]], add);
    }
}

__global__ void finalize2_k(const ull* __restrict__ packed, int* __restrict__ cnt,
                            float* __restrict__ dinv, int n) {
    int i = blockIdx.x * blockDim.x + threadIdx.x;
    if (i >= n) return;
    ull p = packed[i];
    cnt[i] = (int)(p >> 40);
    float deg = (float)(p & MASK40) * (1.0f / 16777216.0f);
    dinv[i] = deg > 0.f ? 1.0f / sqrtf(deg) : 0.f;
}

// inclusive scan within 256-blocks; block totals to bsum  (verbatim round-3)
__global__ __launch_bounds__(256) void scan1_k(const int* __restrict__ cnt,
                                               int* __restrict__ off, int* __restrict__ bsum) {
    __shared__ int s[256];
    int i = blockIdx.x * 256 + threadIdx.x;
    int v = (i < N_NODES) ? cnt[i] : 0;
    s[threadIdx.x] = v;
    __syncthreads();
    for (int d = 1; d < 256; d <<= 1) {
        int t = (threadIdx.x >= d) ? s[threadIdx.x - d] : 0;
        __syncthreads();
        s[threadIdx.x] += t;
        __syncthreads();
    }
    if (i < N_NODES) off[i] = s[threadIdx.x];
    if (threadIdx.x == 255) bsum[blockIdx.x] = s[255];
}

// exclusive scan of the 391 block sums (single block)  (verbatim round-3)
__global__ __launch_bounds__(512) void scan2_k(int* __restrict__ bsum) {
    __shared__ int s[512];
    int v = (threadIdx.x < SCAN_BLKS) ? bsum[threadIdx.x] : 0;
    s[threadIdx.x] = v;
    __syncthreads();
    for (int d = 1; d < 512; d <<= 1) {
        int t = (threadIdx.x >= d) ? s[threadIdx.x - d] : 0;
        __syncthreads();
        s[threadIdx.x] += t;
        __syncthreads();
    }
    if (threadIdx.x < SCAN_BLKS) bsum[threadIdx.x] = s[threadIdx.x] - v;
}

// convert to global exclusive offsets  (verbatim round-3)
__global__ void scan3_k(const int* __restrict__ cnt, int* __restrict__ off,
                        const int* __restrict__ bsum) {
    int i = blockIdx.x * 256 + threadIdx.x;
    if (i < N_NODES) off[i] = off[i] - cnt[i] + bsum[blockIdx.x];
}

// scatter edges into CSR order; post-increment turns off[] into segment ENDS:
// after this kernel, segment(n) = [ n ? off[n-1] : 0,  off[n] )   (verbatim round-3)
__global__ void scatter_k(const int* __restrict__ row, const int* __restrict__ col,
                          const float* __restrict__ ew, const float* __restrict__ dinv,
                          int* __restrict__ off, int2* __restrict__ edat, int E) {
    int e = blockIdx.x * blockDim.x + threadIdx.x;
    if (e >= E) return;
    int c = col[e], r = row[e];
    int pos = atomicAdd(&off[c], 1);
    float nm = dinv[r] * ew[e] * dinv[c];
    edat[pos] = make_int2(r, __float_as_int(nm));
}

__global__ void f2b_k(const float* __restrict__ in, bf16* __restrict__ out, int n) {
    int i = blockIdx.x * blockDim.x + threadIdx.x;
    if (i < n) out[i] = __float2bfloat16(in[i]);
}

// ---------- gather propagation (verbatim round-3: unroll-4, bf16 pair lanes) ----------
__global__ __launch_bounds__(256) void gath32_k(const int2* __restrict__ edat,
                                                const int* __restrict__ off,
                                                const unsigned* __restrict__ src,
                                                unsigned* __restrict__ dst, int nn) {
    int t = blockIdx.x * 256 + threadIdx.x;
    int n = t >> 4;
    if (n >= nn) return;
    int fp = t & 15;  // pair index within row of 16 uints
    int s = (n == 0) ? 0 : off[n - 1];
    int e = off[n];
    float a0 = 0.f, a1 = 0.f, b0 = 0.f, b1 = 0.f;
    int i = s;
    for (; i + 4 <= e; i += 4) {
        int2 v0 = edat[i], v1 = edat[i + 1], v2 = edat[i + 2], v3 = edat[i + 3];
        unsigned s0 = src[v0.x * 16 + fp];
        unsigned s1 = src[v1.x * 16 + fp];
        unsigned s2 = src[v2.x * 16 + fp];
        unsigned s3 = src[v3.x * 16 + fp];
        float n0 = __int_as_float(v0.y), n1 = __int_as_float(v1.y);
        float n2 = __int_as_float(v2.y), n3 = __int_as_float(v3.y);
        a0 += n0 * blo(s0); a1 += n0 * bhi(s0);
        b0 += n1 * blo(s1); b1 += n1 * bhi(s1);
        a0 += n2 * blo(s2); a1 += n2 * bhi(s2);
        b0 += n3 * blo(s3); b1 += n3 * bhi(s3);
    }
    for (; i < e; ++i) {
        int2 v = edat[i];
        unsigned sv = src[v.x * 16 + fp];
        float nm = __int_as_float(v.y);
        a0 += nm * blo(sv); a1 += nm * bhi(sv);
    }
    a0 += b0; a1 += b1;
    dst[n * 16 + fp] = packbf(a0, a1);
}

__global__ __launch_bounds__(256) void gath64_k(const int2* __restrict__ edat,
                                                const int* __restrict__ off,
                                                const unsigned* __restrict__ src,
                                                unsigned* __restrict__ dst, int nn) {
    int t = blockIdx.x * 256 + threadIdx.x;
    int n = t >> 5;
    if (n >= nn) return;
    int fp = t & 31;  // pair index within row of 32 uints
    int s = (n == 0) ? 0 : off[n - 1];
    int e = off[n];
    float a0 = 0.f, a1 = 0.f, b0 = 0.f, b1 = 0.f;
    int i = s;
    for (; i + 4 <= e; i += 4) {
        int2 v0 = edat[i], v1 = edat[i + 1], v2 = edat[i + 2], v3 = edat[i + 3];
        unsigned s0 = src[v0.x * 32 + fp];
        unsigned s1 = src[v1.x * 32 + fp];
        unsigned s2 = src[v2.x * 32 + fp];
        unsigned s3 = src[v3.x * 32 + fp];
        float n0 = __int_as_float(v0.y), n1 = __int_as_float(v1.y);
        float n2 = __int_as_float(v2.y), n3 = __int_as_float(v3.y);
        a0 += n0 * blo(s0); a1 += n0 * bhi(s0);
        b0 += n1 * blo(s1); b1 += n1 * bhi(s1);
        a0 += n2 * blo(s2); a1 += n2 * bhi(s2);
        b0 += n3 * blo(s3); b1 += n3 * bhi(s3);
    }
    for (; i < e; ++i) {
        int2 v = edat[i];
        unsigned sv = src[v.x * 32 + fp];
        float nm = __int_as_float(v.y);
        a0 += nm * blo(sv); a1 += nm * bhi(sv);
    }
    a0 += b0; a1 += b1;
    dst[n * 32 + fp] = packbf(a0, a1);
}

// ---------- dense layers (verbatim round-3) ----------
__global__ __launch_bounds__(256) void dense1_k(const bf16* __restrict__ xb,
                                                const bf16* __restrict__ p1,
                                                const bf16* __restrict__ p2,
                                                const float* __restrict__ w,
                                                const float* __restrict__ b,
                                                bf16* __restrict__ h1) {
    __shared__ float sw[3 * IN_F * HID];  // 24 KB
    __shared__ float sx[4][3 * IN_F];
    for (int i = threadIdx.x; i < 3 * IN_F * HID; i += 256) sw[i] = w[i];
    int nb = blockIdx.x * 4;
    for (int k = threadIdx.x; k < 4 * 96; k += 256) {
        int ln = k / 96, j = k % 96;
        int n = nb + ln;
        float v = 0.f;
        if (n < N_NODES) {
            int hop = j >> 5, ii = j & 31;
            const bf16* sp = (hop == 0) ? xb : (hop == 1 ? p1 : p2);
            v = b2f(sp[n * IN_F + ii]);
        }
        sx[ln][j] = v;
    }
    __syncthreads();
    int ln = threadIdx.x >> 6;
    int n = nb + ln;
    if (n >= N_NODES) return;
    int f = threadIdx.x & 63;
    float acc = b[f];
#pragma unroll 8
    for (int j = 0; j < 96; ++j) acc += sx[ln][j] * sw[j * HID + f];
    acc = acc > 0.f ? acc : 0.01f * acc;
    h1[n * HID + f] = __float2bfloat16(acc);
}

__global__ __launch_bounds__(256) void dense2_k(const bf16* __restrict__ h1,
                                                const bf16* __restrict__ q1,
                                                const bf16* __restrict__ q2,
                                                const float* __restrict__ w,
                                                const float* __restrict__ b,
                                                float* __restrict__ ap) {
    __shared__ float sw[3 * HID * HID];  // 48 KB
    __shared__ float sx[4][3 * HID];
    for (int i = threadIdx.x; i < 3 * HID * HID; i += 256) sw[i] = w[i];
    int nb = blockIdx.x * 4;
    for (int k = threadIdx.x; k < 4 * 192; k += 256) {
        int ln = k / 192, j = k % 192;
        int n = nb + ln;
        float v = 0.f;
        if (n < NUM_APS) {
            int hop = j >> 6, ii = j & 63;
            const bf16* sp = (hop == 0) ? h1 : (hop == 1 ? q1 : q2);
            v = b2f(sp[n * HID + ii]);
        }
        sx[ln][j] = v;
    }
    __syncthreads();
    int ln = threadIdx.x >> 6;
    int n = nb + ln;
    if (n >= NUM_APS) return;
    int f = threadIdx.x & 63;
    float acc = b[f];
#pragma unroll 8
    for (int j = 0; j < 192; ++j) acc += sx[ln][j] * sw[j * HID + f];
    acc = acc > 0.f ? acc : 0.01f * acc;
    ap[n * HID + f] = acc;
}

// two 64->3 heads (verbatim round-3)
__global__ void logits_k(const float* __restrict__ ap,
                         const float* __restrict__ wch, const float* __restrict__ bch,
                         const float* __restrict__ wpw, const float* __restrict__ bpw,
                         float* __restrict__ out) {
    int idx = blockIdx.x * blockDim.x + threadIdx.x;
    if (idx >= NUM_APS * 6) return;
    int n = idx / 6, j = idx % 6;
    const float* w;
    float bb;
    float* o;
    if (j < 3) {
        w = wch + j; bb = bch[j]; o = out + n * 3 + j;
    } else {
        int jj = j - 3;
        w = wpw + jj; bb = bpw[jj]; o = out + NUM_APS * 3 + n * 3 + jj;
    }
    float acc = bb;
    const float* a = ap + n * HID;
#pragma unroll
    for (int i = 0; i < HID; ++i) acc += a[i] * w[i * 3];
    *o = acc;
}

extern "C" void kernel_launch(void* const* d_in, const int* in_sizes, int n_in,
                              void* d_out, int out_size, void* d_ws, size_t ws_size,
                              hipStream_t stream) {
    const float* x   = (const float*)d_in[0];
    const int*   ei  = (const int*)d_in[1];
    const float* ea  = (const float*)d_in[2];
    const float* w1  = (const float*)d_in[3];
    const float* b1  = (const float*)d_in[4];
    const float* w2  = (const float*)d_in[5];
    const float* b2  = (const float*)d_in[6];
    const float* wch = (const float*)d_in[7];
    const float* bch = (const float*)d_in[8];
    const float* wpw = (const float*)d_in[9];
    const float* bpw = (const float*)d_in[10];

    const int E = in_sizes[2];  // 1,600,000
    const int* row  = ei;
    const int* colv = ei + E;

    // ---- workspace layout (float units), ~47.6 MB ----
    // edat 3.2M | packed 0.2M | off 0.1M | cnt 0.1M | dinv 0.1M | bsum 512 |
    // xb 1.6M | p1 1.6M | p2 1.6M | h1 3.2M | q1 overlays p1∪p2 | q2 32K | ap 64K
    float* ws = (float*)d_ws;
    int2*  edat   = (int2*)ws;                     // [0, 3.2M)
    ull*   packed = (ull*)(ws + 3200000);          // [3.2M, 3.4M)
    int*   off    = (int*)(ws + 3400000);          // [3.4M, 3.5M)
    int*   cnt    = (int*)(ws + 3500000);          // [3.5M, 3.6M)
    float* dinv   = ws + 3600000;                  // [3.6M, 3.7M)
    int*   bsum   = (int*)(ws + 3700000);          // 512
    bf16*  xb     = (bf16*)(ws + 3800000);         // N*32 bf16 [3.8M, 5.4M)
    bf16*  p1b    = xb + (size_t)N_NODES * IN_F;   // [5.4M, 7.0M)
    bf16*  p2b    = p1b + (size_t)N_NODES * IN_F;  // [7.0M, 8.6M)
    bf16*  h1b    = p2b + (size_t)N_NODES * IN_F;  // N*64 bf16 [8.6M, 11.8M)
    bf16*  q1b    = p1b;                           // reuse p1∪p2 (N*64 bf16)
    bf16*  q2b    = (bf16*)(ws + 11800000);        // 64000 bf16
    float* ap     = ws + 11832000;                 // 64000 f32

    // ---- CSR build: one packed atomic per edge, then scans + scatter ----
    hipMemsetAsync(packed, 0, (size_t)N_NODES * sizeof(ull), stream);
    cntdeg_pack_k<<<(E + 255) / 256, 256, 0, stream>>>(colv, ea, packed, E);
    finalize2_k<<<SCAN_BLKS, 256, 0, stream>>>(packed, cnt, dinv, N_NODES);
    scan1_k<<<SCAN_BLKS, 256, 0, stream>>>(cnt, off, bsum);
    scan2_k<<<1, 512, 0, stream>>>(bsum);
    scan3_k<<<SCAN_BLKS, 256, 0, stream>>>(cnt, off, bsum);
    scatter_k<<<(E + 255) / 256, 256, 0, stream>>>(row, colv, ea, dinv, off, edat, E);

    // ---- layer 1 (16 pair-lanes per node) ----
    f2b_k<<<(N_NODES * IN_F + 255) / 256, 256, 0, stream>>>(x, xb, N_NODES * IN_F);
    gath32_k<<<(N_NODES * 16 + 255) / 256, 256, 0, stream>>>(edat, off, (unsigned*)xb,
                                                             (unsigned*)p1b, N_NODES);
    gath32_k<<<(N_NODES * 16 + 255) / 256, 256, 0, stream>>>(edat, off, (unsigned*)p1b,
                                                             (unsigned*)p2b, N_NODES);
    dense1_k<<<(N_NODES + 3) / 4, 256, 0, stream>>>(xb, p1b, p2b, w1, b1, h1b);

    // ---- layer 2 (32 pair-lanes per node) ----
    gath64_k<<<(N_NODES * 32 + 255) / 256, 256, 0, stream>>>(edat, off, (unsigned*)h1b,
                                                             (unsigned*)q1b, N_NODES);
    gath64_k<<<(NUM_APS * 32 + 255) / 256, 256, 0, stream>>>(edat, off, (unsigned*)q1b,
                                                             (unsigned*)q2b, NUM_APS);
    dense2_k<<<(NUM_APS + 3) / 4, 256, 0, stream>>>(h1b, q1b, q2b, w2, b2, ap);

    // ---- heads ----
    logits_k<<<(NUM_APS * 6 + 255) / 256, 256, 0, stream>>>(ap, wch, bch, wpw, bpw,
                                                            (float*)d_out);
}